// Round 2
// baseline (63.003 us; speedup 1.0000x reference)
//
#include <hip/hip_runtime.h>
#include <math.h>

// SNN forward: ConstantCurrentLIFEncoder -> LIFCell -> LILinearCell, T=32.
//
// One WAVE (64 lanes) per batch row; 4 waves/block; no __syncthreads.
// Each lane loads up to 4 float4 (row = 196 aligned float4s), nontemporally:
// the image is touched exactly once and the harness's 256 MiB workspace
// poison has just left L2/L3 full of dirty lines — NT loads skip cache
// allocation so reads don't pay dirty-victim writebacks.
//
// Exact event-driven shortcut: encoder membrane obeys v' = 0.9 v + 0.1 x
// (convex combination => v <= x always, incl. fp32 rounding). Spike needs
// v > 1.0 strictly, so if all x <= 1.0 in the row the encoder never fires,
// the hidden layer (zero-init) stays silent, v_out == 0 for all t, and the
// output row is the constant log_softmax(0) = -log(10).
//
// Rows failing the gate run the full 32-step simulation ENTIRELY IN
// REGISTERS (fully unrolled, compile-time indices only — no scratch, no
// global workspace). The fast path never touches it.

#define N_IN    784
#define N_OUT   10
#define T_STEPS 32

// native clang vector type: __builtin_nontemporal_load requires a pointer
// to scalar/vector-of-scalar, not HIP's HIP_vector_type class.
typedef float floatx4 __attribute__((ext_vector_type(4)));

__global__ __launch_bounds__(256) void snn_wave_kernel(
    const float* __restrict__ image,   // [B, 784]
    const float* __restrict__ W,       // [10, 784]
    float* __restrict__ out,           // [B, 10]
    int B)
{
    constexpr float DT_TMI  = 0.1f;    // DT * TAU_MEM_INV (exact fp32 match)
    constexpr float DEC_SYN = 0.8f;    // 1 - DT * TAU_SYN_INV
    constexpr float V_TH    = 1.0f;
    constexpr float NEG_LOG10 = -2.30258509299404568402f;

    const int wave = threadIdx.x >> 6;
    const int lane = threadIdx.x & 63;
    const int row  = blockIdx.x * 4 + wave;
    if (row >= B) return;                       // wave-uniform

    const floatx4* __restrict__ x4 = (const floatx4*)(image + (size_t)row * N_IN);

    // lane's chunks: lane, lane+64, lane+128, and (lane<4) lane+192
    const bool has4 = (lane < 4);
    floatx4 c0 = __builtin_nontemporal_load(x4 + lane);
    floatx4 c1 = __builtin_nontemporal_load(x4 + lane + 64);
    floatx4 c2 = __builtin_nontemporal_load(x4 + lane + 128);
    floatx4 c3 = (floatx4)(0.f);
    if (has4) c3 = __builtin_nontemporal_load(x4 + lane + 192);

    // gate: any x > V_TH anywhere in the row?
    float m = fmaxf(fmaxf(fmaxf(c0.x, c0.y), fmaxf(c0.z, c0.w)),
                    fmaxf(fmaxf(c1.x, c1.y), fmaxf(c1.z, c1.w)));
    m = fmaxf(m, fmaxf(fmaxf(c2.x, c2.y), fmaxf(c2.z, c2.w)));
    m = fmaxf(m, fmaxf(fmaxf(c3.x, c3.y), fmaxf(c3.z, c3.w)));

    if (!__any(m > V_TH)) {
        // Exact output: log_softmax of the all-zero v_max vector.
        if (lane < N_OUT)
            __builtin_nontemporal_store(NEG_LOG10, out + (size_t)row * N_OUT + lane);
        return;
    }

    // ---------------- rare path: full 32-step simulation ----------------
    // All state in registers; every array index is compile-time constant.
    float xv[16] = { c0.x, c0.y, c0.z, c0.w,  c1.x, c1.y, c1.z, c1.w,
                     c2.x, c2.y, c2.z, c2.w,  c3.x, c3.y, c3.z, c3.w };
    float ve[16], vh[16], ih[16];
#pragma unroll
    for (int k = 0; k < 16; ++k) { ve[k] = 0.f; vh[k] = 0.f; ih[k] = 0.f; }

    float vo[N_OUT], io[N_OUT], vmax[N_OUT];
#pragma unroll
    for (int o = 0; o < N_OUT; ++o) { vo[o] = 0.f; io[o] = 0.f; vmax[o] = -INFINITY; }

    for (int t = 0; t < T_STEPS; ++t) {
        float s[N_OUT];
#pragma unroll
        for (int o = 0; o < N_OUT; ++o) s[o] = 0.f;

#pragma unroll
        for (int cc = 0; cc < 4; ++cc) {
            // neuron float4-index for this chunk; lanes >= 4 never own a
            // 4th chunk (x == 0 there => never spikes), clamp their j
            // in-bounds so even a speculated W load is safe.
            const int gbase = (cc < 3) ? (lane + 64 * cc)
                                       : (has4 ? (192 + lane) : 0);
#pragma unroll
            for (int e = 0; e < 4; ++e) {
                const int k = 4 * cc + e;
                const int j = 4 * gbase + e;
                const float x = xv[k];
                // encoder LIF
                float v = ve[k];
                v += DT_TMI * (x - v);
                const float z_enc = (v > V_TH) ? 1.0f : 0.0f;
                ve[k] = (v > V_TH) ? 0.0f : v;
                // hidden LIF
                const float vd = vh[k] + DT_TMI * (ih[k] - vh[k]);
                const float id = DEC_SYN * ih[k];
                const bool  z0 = vd > V_TH;
                vh[k] = z0 ? 0.0f : vd;
                ih[k] = id + z_enc;
                if (z0) {
#pragma unroll
                    for (int o = 0; o < N_OUT; ++o) s[o] += W[o * N_IN + j];
                }
            }
        }

        // butterfly reduce: ALL lanes get the 10 full spike-weight sums
#pragma unroll
        for (int o = 0; o < N_OUT; ++o) {
            float v = s[o];
            v += __shfl_xor(v, 32, 64);
            v += __shfl_xor(v, 16, 64);
            v += __shfl_xor(v,  8, 64);
            v += __shfl_xor(v,  4, 64);
            v += __shfl_xor(v,  2, 64);
            v += __shfl_xor(v,  1, 64);
            s[o] = v;
        }

        // readout (wave-uniform, redundant on all lanes — no scratch)
#pragma unroll
        for (int o = 0; o < N_OUT; ++o) {
            const float jump = io[o] + s[o];
            const float v    = vo[o] + DT_TMI * (jump - vo[o]);
            vo[o]   = v;
            io[o]   = DEC_SYN * jump;
            vmax[o] = fmaxf(vmax[o], v);
        }
    }

    float mm = -INFINITY;
#pragma unroll
    for (int o = 0; o < N_OUT; ++o) mm = fmaxf(mm, vmax[o]);
    float sum = 0.0f;
#pragma unroll
    for (int o = 0; o < N_OUT; ++o) sum += expf(vmax[o] - mm);
    const float lse = mm + logf(sum);

    // lane o stores vmax[o] - lse; select with compile-time indices
    float myv = vmax[0];
#pragma unroll
    for (int o = 1; o < N_OUT; ++o) myv = (lane == o) ? vmax[o] : myv;
    if (lane < N_OUT) out[(size_t)row * N_OUT + lane] = myv - lse;
}

extern "C" void kernel_launch(void* const* d_in, const int* in_sizes, int n_in,
                              void* d_out, int out_size, void* d_ws, size_t ws_size,
                              hipStream_t stream) {
    const float* image = (const float*)d_in[0];   // [4096,1,28,28] fp32
    const float* W     = (const float*)d_in[1];   // [10,784] fp32
    float*       out   = (float*)d_out;           // [4096,10] fp32
    (void)d_ws; (void)ws_size;                    // workspace unused

    const int B = in_sizes[0] / N_IN;             // 4096
    const int blocks = (B + 3) / 4;               // one wave per row
    snn_wave_kernel<<<blocks, 256, 0, stream>>>(image, W, out, B);
}

// Round 3
// 62.280 us; speedup vs baseline: 1.0116x; 1.0116x over previous
//
#include <hip/hip_runtime.h>
#include <math.h>

// SNN forward: ConstantCurrentLIFEncoder -> LIFCell -> LILinearCell, T=32.
//
// One WAVE (64 lanes) per batch row; 4 waves/block; no __syncthreads.
// Each lane loads 4 float4 (row = 196 aligned float4s; the 4th chunk is
// clamped in-bounds for lanes >= 4 and forced to zero). Loads are REGULAR
// (cache-eligible): the image is iteration-invariant, so any lines that
// survive the harness's 256 MiB poison sweep in L3 are free hits — NT
// loads (tried in a previous round) forfeit those and measured slower.
//
// Exact event-driven shortcut: encoder membrane obeys v' = 0.9 v + 0.1 x
// (convex combination => v <= x always, incl. fp32 rounding). Spike needs
// v > 1.0 strictly, so if all x <= 1.0 in the row the encoder never fires,
// the hidden layer (zero-init) stays silent, v_out == 0 for all t, and the
// output row is the constant log_softmax(0) = -log(10).
//
// Rows failing the gate run the full 32-step simulation ENTIRELY IN
// REGISTERS (fully unrolled, compile-time indices only — no scratch, no
// global workspace). The fast path never touches it.

#define N_IN    784
#define N_OUT   10
#define T_STEPS 32

typedef float floatx4 __attribute__((ext_vector_type(4)));

__global__ __launch_bounds__(256) void snn_wave_kernel(
    const float* __restrict__ image,   // [B, 784]
    const float* __restrict__ W,       // [10, 784]
    float* __restrict__ out,           // [B, 10]
    int B)
{
    constexpr float DT_TMI  = 0.1f;    // DT * TAU_MEM_INV (exact fp32 match)
    constexpr float DEC_SYN = 0.8f;    // 1 - DT * TAU_SYN_INV
    constexpr float V_TH    = 1.0f;
    constexpr float NEG_LOG10 = -2.30258509299404568402f;

    const int wave = threadIdx.x >> 6;
    const int lane = threadIdx.x & 63;
    const int row  = blockIdx.x * 4 + wave;
    if (row >= B) return;                       // wave-uniform

    const floatx4* __restrict__ x4 = (const floatx4*)(image + (size_t)row * N_IN);

    // lane's chunks: lane, lane+64, lane+128, and (lane<4) lane+192.
    // 4th load is issued unconditionally at a clamped in-bounds address
    // (no exec-mask branch); lanes >= 4 zero it out afterwards.
    const bool has4 = (lane < 4);
    const floatx4 c0 = x4[lane];
    const floatx4 c1 = x4[lane + 64];
    const floatx4 c2 = x4[lane + 128];
    floatx4 c3 = x4[has4 ? (lane + 192) : lane];
    if (!has4) c3 = (floatx4)(0.f);

    // gate: any x > V_TH anywhere in the row?
    float m = fmaxf(fmaxf(fmaxf(c0.x, c0.y), fmaxf(c0.z, c0.w)),
                    fmaxf(fmaxf(c1.x, c1.y), fmaxf(c1.z, c1.w)));
    m = fmaxf(m, fmaxf(fmaxf(c2.x, c2.y), fmaxf(c2.z, c2.w)));
    m = fmaxf(m, fmaxf(fmaxf(c3.x, c3.y), fmaxf(c3.z, c3.w)));

    if (!__any(m > V_TH)) {
        // Exact output: log_softmax of the all-zero v_max vector.
        if (lane < N_OUT)
            __builtin_nontemporal_store(NEG_LOG10, out + (size_t)row * N_OUT + lane);
        return;
    }

    // ---------------- rare path: full 32-step simulation ----------------
    // All state in registers; every array index is compile-time constant.
    float xv[16] = { c0.x, c0.y, c0.z, c0.w,  c1.x, c1.y, c1.z, c1.w,
                     c2.x, c2.y, c2.z, c2.w,  c3.x, c3.y, c3.z, c3.w };
    float ve[16], vh[16], ih[16];
#pragma unroll
    for (int k = 0; k < 16; ++k) { ve[k] = 0.f; vh[k] = 0.f; ih[k] = 0.f; }

    float vo[N_OUT], io[N_OUT], vmax[N_OUT];
#pragma unroll
    for (int o = 0; o < N_OUT; ++o) { vo[o] = 0.f; io[o] = 0.f; vmax[o] = -INFINITY; }

    for (int t = 0; t < T_STEPS; ++t) {
        float s[N_OUT];
#pragma unroll
        for (int o = 0; o < N_OUT; ++o) s[o] = 0.f;

#pragma unroll
        for (int cc = 0; cc < 4; ++cc) {
            // neuron float4-index for this chunk; lanes >= 4 never own a
            // 4th chunk (x == 0 there => never spikes), clamp their j
            // in-bounds so even a speculated W load is safe.
            const int gbase = (cc < 3) ? (lane + 64 * cc)
                                       : (has4 ? (192 + lane) : 0);
#pragma unroll
            for (int e = 0; e < 4; ++e) {
                const int k = 4 * cc + e;
                const int j = 4 * gbase + e;
                const float x = xv[k];
                // encoder LIF
                float v = ve[k];
                v += DT_TMI * (x - v);
                const float z_enc = (v > V_TH) ? 1.0f : 0.0f;
                ve[k] = (v > V_TH) ? 0.0f : v;
                // hidden LIF
                const float vd = vh[k] + DT_TMI * (ih[k] - vh[k]);
                const float id = DEC_SYN * ih[k];
                const bool  z0 = vd > V_TH;
                vh[k] = z0 ? 0.0f : vd;
                ih[k] = id + z_enc;
                if (z0) {
#pragma unroll
                    for (int o = 0; o < N_OUT; ++o) s[o] += W[o * N_IN + j];
                }
            }
        }

        // butterfly reduce: ALL lanes get the 10 full spike-weight sums
#pragma unroll
        for (int o = 0; o < N_OUT; ++o) {
            float v = s[o];
            v += __shfl_xor(v, 32, 64);
            v += __shfl_xor(v, 16, 64);
            v += __shfl_xor(v,  8, 64);
            v += __shfl_xor(v,  4, 64);
            v += __shfl_xor(v,  2, 64);
            v += __shfl_xor(v,  1, 64);
            s[o] = v;
        }

        // readout (wave-uniform, redundant on all lanes — no scratch)
#pragma unroll
        for (int o = 0; o < N_OUT; ++o) {
            const float jump = io[o] + s[o];
            const float v    = vo[o] + DT_TMI * (jump - vo[o]);
            vo[o]   = v;
            io[o]   = DEC_SYN * jump;
            vmax[o] = fmaxf(vmax[o], v);
        }
    }

    float mm = -INFINITY;
#pragma unroll
    for (int o = 0; o < N_OUT; ++o) mm = fmaxf(mm, vmax[o]);
    float sum = 0.0f;
#pragma unroll
    for (int o = 0; o < N_OUT; ++o) sum += expf(vmax[o] - mm);
    const float lse = mm + logf(sum);

    // lane o stores vmax[o] - lse; select with compile-time indices
    float myv = vmax[0];
#pragma unroll
    for (int o = 1; o < N_OUT; ++o) myv = (lane == o) ? vmax[o] : myv;
    if (lane < N_OUT) out[(size_t)row * N_OUT + lane] = myv - lse;
}

extern "C" void kernel_launch(void* const* d_in, const int* in_sizes, int n_in,
                              void* d_out, int out_size, void* d_ws, size_t ws_size,
                              hipStream_t stream) {
    const float* image = (const float*)d_in[0];   // [4096,1,28,28] fp32
    const float* W     = (const float*)d_in[1];   // [10,784] fp32
    float*       out   = (float*)d_out;           // [4096,10] fp32
    (void)d_ws; (void)ws_size;                    // workspace unused

    const int B = in_sizes[0] / N_IN;             // 4096
    const int blocks = (B + 3) / 4;               // one wave per row
    snn_wave_kernel<<<blocks, 256, 0, stream>>>(image, W, out, B);
}